// Round 2
// baseline (1053.714 us; speedup 1.0000x reference)
//
#include <hip/hip_runtime.h>
#include <hip/hip_bf16.h>

typedef __attribute__((ext_vector_type(8))) short bf16x8;
typedef __attribute__((ext_vector_type(4))) float f32x4;
typedef __attribute__((ext_vector_type(4))) _Float16 f16x4;
typedef __attribute__((ext_vector_type(4))) unsigned short u16x4;

#define B_ 2
#define S_ 2048
#define E_ 2048
#define H_ 16
#define D_ 128
#define ELEMS (B_*S_*E_)   // 8388608 elements of [B,S,2048]
#define WELEMS (E_*E_)     // 4194304 elements per weight matrix

__device__ __forceinline__ unsigned short f2bf(float x) {
  unsigned int u = __float_as_uint(x);
  u += 0x7fffu + ((u >> 16) & 1u);
  return (unsigned short)(u >> 16);
}

__device__ __forceinline__ void async_load16(const void* g, void* l) {
  __builtin_amdgcn_global_load_lds(
      (const __attribute__((address_space(1))) unsigned int*)g,
      (__attribute__((address_space(3))) unsigned int*)l, 16, 0, 0);
}

// f32 -> bf16 (RNE), vectorized x4. n4 = n/4.
__global__ __launch_bounds__(256)
void cvt_f32_bf16(const float* __restrict__ src, unsigned short* __restrict__ dst, int n4)
{
  const int i = blockIdx.x * 256 + threadIdx.x;
  if (i < n4) {
    const f32x4 v = ((const f32x4*)src)[i];
    u16x4 o;
    o.x = f2bf(v.x); o.y = f2bf(v.y); o.z = f2bf(v.z); o.w = f2bf(v.w);
    ((u16x4*)dst)[i] = o;
  }
}

// C[m][n] = sum_k A[m][k] * Bw[n][k]   (torch Linear / B^T layout), bf16 in,
// f32 accumulate, output bf16 or f32. m97-ladder structure (128x128, BK=32).
template<bool F32OUT>
__global__ __launch_bounds__(256)
void gemm_bt(const __hip_bfloat16* __restrict__ A,
             const __hip_bfloat16* __restrict__ Bw,
             void* __restrict__ C, int M, int N, int K)
{
  __shared__ __hip_bfloat16 As[128*32];
  __shared__ __hip_bfloat16 Bs[128*32];
  const int tid  = threadIdx.x;
  const int lane = tid & 63;
  const int w    = tid >> 6;
  const int m0 = blockIdx.y * 128;
  const int n0 = blockIdx.x * 128;
  const int wm = (w >> 1) * 64;
  const int wn = (w & 1) * 64;
  const int lrow = lane >> 2;        // staging: row within 16-row chunk
  const int lcol = (lane & 3) * 8;   // staging: col (8 bf16 = 16 B)
  const int fr = lane & 15;          // MFMA frag row
  const int fg = lane >> 4;          // MFMA frag k-group

  f32x4 acc[4][4];
#pragma unroll
  for (int i = 0; i < 4; i++)
#pragma unroll
    for (int j = 0; j < 4; j++) acc[i][j] = (f32x4)0.0f;

  for (int k0 = 0; k0 < K; k0 += 32) {
    __syncthreads();
#pragma unroll
    for (int s = 0; s < 2; s++) {
      const int rbase = s*64 + w*16;   // wave-uniform LDS base; HW adds lane*16B
      async_load16(A  + (size_t)(m0 + rbase + lrow)*K + k0 + lcol, As + rbase*32);
      async_load16(Bw + (size_t)(n0 + rbase + lrow)*K + k0 + lcol, Bs + rbase*32);
    }
    __syncthreads();
    bf16x8 af[4], bfr[4];
#pragma unroll
    for (int i = 0; i < 4; i++) {
      af[i]  = *(const bf16x8*)(As + (wm + i*16 + fr)*32 + fg*8);
      bfr[i] = *(const bf16x8*)(Bs + (wn + i*16 + fr)*32 + fg*8);
    }
#pragma unroll
    for (int i = 0; i < 4; i++)
#pragma unroll
      for (int j = 0; j < 4; j++)
        acc[i][j] = __builtin_amdgcn_mfma_f32_16x16x32_bf16(af[i], bfr[j], acc[i][j], 0, 0, 0);
  }

#pragma unroll
  for (int i = 0; i < 4; i++) {
    const int row = m0 + wm + i*16 + fg*4;
#pragma unroll
    for (int j = 0; j < 4; j++) {
      const int col = n0 + wn + j*16 + fr;
#pragma unroll
      for (int r = 0; r < 4; r++) {
        if (F32OUT) ((float*)C)[(size_t)(row + r)*N + col] = acc[i][j][r];
        else ((unsigned short*)C)[(size_t)(row + r)*N + col] = f2bf(acc[i][j][r]);
      }
    }
  }
}

// xpos rotary, in place on bf16 Q and K. One thread per (b,s,h,pair).
__global__ __launch_bounds__(256)
void xpos_rotary(__hip_bfloat16* __restrict__ Q, __hip_bfloat16* __restrict__ Kt)
{
  const int idx = blockIdx.x * 256 + threadIdx.x;   // [0, B*S*H*64)
  const int j = idx & 63;                            // pair index within head
  const int s = (idx >> 10) & 2047;                  // sequence position
  const float seq = (float)(s - 1024) * (1.0f/512.0f);
  const float dr = 2.0f + 2.0f*(float)j;
  // theta = (1/10000)^(dr/128) = exp(dr/128 * ln(1e-4))
  const float theta = expf(dr * (1.0f/128.0f) * -9.210340371976184f);
  const float zeta  = (dr * (1.0f/64.0f) + 51.2f) * (1.0f/52.2f);
  const float ang = seq * theta;
  const float c  = cosf(ang);
  const float sn = sinf(ang);
  const float t  = expf(seq * logf(zeta));
  const float it = 1.0f / t;

  const size_t base = (size_t)(idx >> 6) * 128 + 2*j;
  unsigned short* Qs = (unsigned short*)Q;
  unsigned short* Ks = (unsigned short*)Kt;
  const float q0 = __bfloat162float(Q[base]),  q1 = __bfloat162float(Q[base+1]);
  Qs[base]   = f2bf((q0*c - q1*sn) * t);
  Qs[base+1] = f2bf((q1*c + q0*sn) * t);
  const float k0 = __bfloat162float(Kt[base]), k1 = __bfloat162float(Kt[base+1]);
  Ks[base]   = f2bf((k0*c - k1*sn) * it);
  Ks[base+1] = f2bf((k1*c + k0*sn) * it);
}

// V [B,S,H,D] bf16 -> VT [B,H,D,S] f16  (f16 for the 16x16x16f16 PV MFMA)
__global__ __launch_bounds__(256)
void transpose_v(const __hip_bfloat16* __restrict__ V, _Float16* __restrict__ VT)
{
  __shared__ float tile[32][33];
  const int tx = threadIdx.x, ty = threadIdx.y;      // block (32, 8)
  const int bh = blockIdx.z;
  const int b = bh >> 4, h = bh & 15;
  const int s0 = blockIdx.x * 32, d0 = blockIdx.y * 32;
#pragma unroll
  for (int r = 0; r < 4; r++) {
    const int s = s0 + ty + r*8;
    tile[ty + r*8][tx] = __bfloat162float(V[((size_t)(b*S_ + s))*E_ + h*D_ + d0 + tx]);
  }
  __syncthreads();
#pragma unroll
  for (int r = 0; r < 4; r++) {
    const int d = d0 + ty + r*8;
    VT[((size_t)(bh*D_ + d))*S_ + s0 + tx] = (_Float16)tile[tx][ty + r*8];
  }
}

// Flash attention, causal. Computes S^T = K*Q^T per 16-key tile so the
// QK^T C-layout (row=key,col=q) is directly the B-operand layout of the
// 16x16x16f16 PV MFMA. O accumulated transposed (O^T[d][q]); per-lane
// softmax state since q = lane&15 for every fragment involved.
__global__ __launch_bounds__(256)
void attn_fwd(const __hip_bfloat16* __restrict__ Q,
              const __hip_bfloat16* __restrict__ K,
              const _Float16* __restrict__ VT,
              __hip_bfloat16* __restrict__ O)
{
  __shared__ float smem[64*128];
  const int lane = threadIdx.x & 63;
  const int w    = threadIdx.x >> 6;
  const int bh = blockIdx.y;
  const int b = bh >> 4, h = bh & 15;
  const int q0 = blockIdx.x*64 + w*16;   // this wave's 16 q rows
  const int qc = lane & 15;              // q column owned by this lane
  const int g  = lane >> 4;              // k-group

  const size_t bh_base = (size_t)b*S_*E_ + h*D_;
  bf16x8 qf[4];
  {
    const __hip_bfloat16* qrow = Q + bh_base + (size_t)(q0 + qc)*E_ + g*8;
#pragma unroll
    for (int c = 0; c < 4; c++) qf[c] = *(const bf16x8*)(qrow + c*32);
  }
  const _Float16* vt = VT + (size_t)bh*D_*S_;

  f32x4 acc_o[8];
#pragma unroll
  for (int t = 0; t < 8; t++) acc_o[t] = (f32x4)0.0f;
  float m_i = -1e30f, l_i = 0.0f;
  const float scale = 0.08838834764831845f;   // 1/sqrt(128)

  const int ntiles = blockIdx.x*4 + w + 1;    // keys 0 .. q0+15 inclusive
  for (int kt = 0; kt < ntiles; ++kt) {
    const int k0 = kt*16;
    const __hip_bfloat16* krow = K + bh_base + (size_t)(k0 + qc)*E_ + g*8;
    f32x4 sacc = (f32x4)0.0f;
#pragma unroll
    for (int c = 0; c < 4; c++) {
      const bf16x8 kf = *(const bf16x8*)(krow + c*32);
      sacc = __builtin_amdgcn_mfma_f32_16x16x32_bf16(kf, qf[c], sacc, 0, 0, 0);
    }
    // scale + causal mask; S^T layout: row(key) = g*4+r, col(q) = qc
    float sv[4];
#pragma unroll
    for (int r = 0; r < 4; r++) {
      const int key = k0 + g*4 + r;
      sv[r] = (key <= q0 + qc) ? sacc[r]*scale : -1e30f;
    }
    float mx = fmaxf(fmaxf(sv[0], sv[1]), fmaxf(sv[2], sv[3]));
    mx = fmaxf(mx, __shfl_xor(mx, 16));
    mx = fmaxf(mx, __shfl_xor(mx, 32));
    const float m_new = fmaxf(m_i, mx);
    const float alpha = __expf(m_i - m_new);
    const float p0 = __expf(sv[0]-m_new), p1 = __expf(sv[1]-m_new),
                p2 = __expf(sv[2]-m_new), p3 = __expf(sv[3]-m_new);
    float ps = p0 + p1 + p2 + p3;
    ps += __shfl_xor(ps, 16);
    ps += __shfl_xor(ps, 32);
    l_i = l_i*alpha + ps;
    m_i = m_new;
    // P in C-layout == B-operand layout for 16x16x16 (k=key): no transpose.
    const f16x4 pf = { (_Float16)p0, (_Float16)p1, (_Float16)p2, (_Float16)p3 };
#pragma unroll
    for (int t = 0; t < 8; t++) {
      const f16x4 vf = *(const f16x4*)(vt + (size_t)(t*16 + qc)*S_ + k0 + g*4);
      acc_o[t] *= alpha;
      acc_o[t] = __builtin_amdgcn_mfma_f32_16x16x16f16(vf, pf, acc_o[t], 0, 0, 0);
    }
  }

  // epilogue: O^T[d][q] -> LDS as O[q][d], then coalesced bf16 store
  const float inv_l = 1.0f / l_i;
#pragma unroll
  for (int t = 0; t < 8; t++)
#pragma unroll
    for (int r = 0; r < 4; r++)
      smem[(w*16 + qc)*128 + t*16 + g*4 + r] = acc_o[t][r] * inv_l;
  __syncthreads();

  const int row = threadIdx.x >> 2;          // 0..63
  const int c0  = (threadIdx.x & 3) * 32;
  unsigned short* Os = (unsigned short*)O;
  const size_t obase = bh_base + (size_t)(blockIdx.x*64 + row)*E_;
#pragma unroll
  for (int i = 0; i < 8; i++) {
    const f32x4 v4 = *(const f32x4*)(smem + row*128 + c0 + i*4);
    u16x4 o4;
    o4.x = f2bf(v4.x); o4.y = f2bf(v4.y); o4.z = f2bf(v4.z); o4.w = f2bf(v4.w);
    *(u16x4*)(Os + obase + c0 + i*4) = o4;
  }
}

extern "C" void kernel_launch(void* const* d_in, const int* in_sizes, int n_in,
                              void* d_out, int out_size, void* d_ws, size_t ws_size,
                              hipStream_t stream)
{
  (void)in_sizes; (void)n_in; (void)out_size; (void)ws_size;
  // Inputs are float32 per the reference dtypes.
  const float* act = (const float*)d_in[0];
  const float* Wq  = (const float*)d_in[1];
  const float* Wk  = (const float*)d_in[2];
  const float* Wv  = (const float*)d_in[3];
  const float* Wo  = (const float*)d_in[4];

  // workspace layout (112 MB):
  // actb(16) Wqb(8) Wkb(8) Wvb(8) Wob(8) Q(16) K(16) V/AO(16) VT(16)
  __hip_bfloat16* actb = (__hip_bfloat16*)d_ws;
  __hip_bfloat16* Wqb  = actb + ELEMS;
  __hip_bfloat16* Wkb  = Wqb + WELEMS;
  __hip_bfloat16* Wvb  = Wkb + WELEMS;
  __hip_bfloat16* Wob  = Wvb + WELEMS;
  __hip_bfloat16* Q    = Wob + WELEMS;
  __hip_bfloat16* Kp   = Q + ELEMS;
  __hip_bfloat16* V    = Kp + ELEMS;
  _Float16*       VT   = (_Float16*)(V + ELEMS);
  __hip_bfloat16* AO   = V;   // V dead after transpose_v; reuse for attn output

  cvt_f32_bf16<<<ELEMS/4/256,  256, 0, stream>>>(act, (unsigned short*)actb, ELEMS/4);
  cvt_f32_bf16<<<WELEMS/4/256, 256, 0, stream>>>(Wq,  (unsigned short*)Wqb,  WELEMS/4);
  cvt_f32_bf16<<<WELEMS/4/256, 256, 0, stream>>>(Wk,  (unsigned short*)Wkb,  WELEMS/4);
  cvt_f32_bf16<<<WELEMS/4/256, 256, 0, stream>>>(Wv,  (unsigned short*)Wvb,  WELEMS/4);
  cvt_f32_bf16<<<WELEMS/4/256, 256, 0, stream>>>(Wo,  (unsigned short*)Wob,  WELEMS/4);

  const dim3 gg(E_/128, (B_*S_)/128);
  gemm_bt<false><<<gg, 256, 0, stream>>>(actb, Wqb, Q,  B_*S_, E_, E_);
  gemm_bt<false><<<gg, 256, 0, stream>>>(actb, Wkb, Kp, B_*S_, E_, E_);
  gemm_bt<false><<<gg, 256, 0, stream>>>(actb, Wvb, V,  B_*S_, E_, E_);
  xpos_rotary<<<(B_*S_*H_*64)/256, 256, 0, stream>>>(Q, Kp);
  transpose_v<<<dim3(S_/32, D_/32, B_*H_), dim3(32, 8), 0, stream>>>(V, VT);
  attn_fwd<<<dim3(S_/64, B_*H_), 256, 0, stream>>>(Q, Kp, VT, AO);
  gemm_bt<true><<<gg, 256, 0, stream>>>(AO, Wob, d_out, B_*S_, E_, E_);
}